// Round 3
// baseline (553.005 us; speedup 1.0000x reference)
//
#include <hip/hip_runtime.h>
#include <hip/hip_cooperative_groups.h>
#include <math.h>

namespace cg = cooperative_groups;

// Sinkhorn [B=32, N=1024, N=1024] fp32, TAU=1, 10 iters.
// v4: persistent cooperative kernel. Grid = 256 blocks (1/CU) x 512 threads.
// Block owns 128 rows of one batch (512 KiB): quads q=0..2 of each lane's
// 16 columns live in VGPRs (x[16][12]), quad 3 lives in LDS (128 KiB, strictly
// thread-private -> no barriers). Natural-log domain, __expf/__logf only
// (the __exp2f name collides with glibc math.h on this toolchain).
// Per iteration: row LSE (CU-local butterflies) -> col partials (LDS merge
// across 8 waves -> global pm/pl) -> ONE grid.sync -> every block merges the
// 8 row-block partials of its batch locally -> Lc. 5 iterations = 10 halves.
// HBM traffic: read s once + write out once + ~10 MiB partials.

#define BATCH 32
#define N 1024
#define RCHUNKS 32
#define ROWS_PER_BLK 32
#define PCHUNKS RCHUNKS

// LDS layout (floats): q3[32768] | Bm[2048] | Bl[2048] | Lcs[1024] = 148 KiB
#define LDS_FLOATS 37888
#define LDS_BYTES  151552

__global__ __launch_bounds__(512, 2) void sinkhorn_coop(
    const float* __restrict__ s, float* __restrict__ out,
    float* __restrict__ pm, float* __restrict__ pl)
{
    extern __shared__ float lds[];
    float4* q3  = (float4*)lds;            // [ (w*16+r)*64 + l ] : quad-3 data
    float*  Bm  = lds + 32768;             // [ (w*4+e)*64 + l ]
    float*  Bl  = Bm + 2048;
    float*  Lcs = Bl + 2048;               // [ storage idx 0..1023 ]

    const int cu = blockIdx.x;
    const int b  = cu >> 3;                // batch
    const int rb = cu & 7;                 // row-block within batch (128 rows)
    const int w  = threadIdx.x >> 6;
    const int l  = threadIdx.x & 63;

    // lane owns cols col(q,e) = 256*q + 4*l + e  (q,e in 0..3)
    const size_t rowbase = ((size_t)b * N + rb * 128 + w * 16) * N;

    // ---------- load: s once, 16 rows x 4 float4 ----------
    float x[16][12];
#pragma unroll
    for (int r = 0; r < 16; ++r) {
        const float4* p = (const float4*)(s + rowbase + (size_t)r * N);
        float4 v0 = p[l];
        float4 v1 = p[64 + l];
        float4 v2 = p[128 + l];
        float4 v3 = p[192 + l];
        x[r][0] = v0.x; x[r][1] = v0.y; x[r][2]  = v0.z; x[r][3]  = v0.w;
        x[r][4] = v1.x; x[r][5] = v1.y; x[r][6]  = v1.z; x[r][7]  = v1.w;
        x[r][8] = v2.x; x[r][9] = v2.y; x[r][10] = v2.z; x[r][11] = v2.w;
        q3[(w*16 + r)*64 + l] = v3;
    }

    float Lc[16];
#pragma unroll
    for (int k = 0; k < 16; ++k) Lc[k] = 0.f;

    cg::grid_group grid = cg::this_grid();

#pragma unroll 1
    for (int it = 0; it < 5; ++it) {
        // ---------- row phase (CU-local): x -= Lc; x -= rowLSE(x) ----------
#pragma unroll
        for (int r = 0; r < 16; ++r) {
            float4 h = q3[(w*16 + r)*64 + l];
#pragma unroll
            for (int k = 0; k < 12; ++k) x[r][k] -= Lc[k];
            h.x -= Lc[12]; h.y -= Lc[13]; h.z -= Lc[14]; h.w -= Lc[15];
            float m = fmaxf(fmaxf(h.x, h.y), fmaxf(h.z, h.w));
#pragma unroll
            for (int k = 0; k < 12; ++k) m = fmaxf(m, x[r][k]);
#pragma unroll
            for (int off = 32; off > 0; off >>= 1) m = fmaxf(m, __shfl_xor(m, off, 64));
            float s0 = __expf(h.x - m) + __expf(h.y - m);
            float s1 = __expf(h.z - m) + __expf(h.w - m);
            float s2 = 0.f, s3 = 0.f;
#pragma unroll
            for (int k = 0; k < 12; k += 4) {
                s0 += __expf(x[r][k]   - m);
                s1 += __expf(x[r][k+1] - m);
                s2 += __expf(x[r][k+2] - m);
                s3 += __expf(x[r][k+3] - m);
            }
            float sum = (s0 + s1) + (s2 + s3);
#pragma unroll
            for (int off = 32; off > 0; off >>= 1) sum += __shfl_xor(sum, off, 64);
            float Lr = m + __logf(sum);
#pragma unroll
            for (int k = 0; k < 12; ++k) x[r][k] -= Lr;
            h.x -= Lr; h.y -= Lr; h.z -= Lr; h.w -= Lr;
            q3[(w*16 + r)*64 + l] = h;
        }

        // ---------- col phase: per-quad partial over this wave's 16 rows ----
#pragma unroll
        for (int q = 0; q < 4; ++q) {
            float cm[4], cl[4];
            if (q < 3) {
#pragma unroll
                for (int e = 0; e < 4; ++e) {
                    const int k = q*4 + e;
                    float m = x[0][k];
#pragma unroll
                    for (int r = 1; r < 16; ++r) m = fmaxf(m, x[r][k]);
                    float acc = 0.f;
#pragma unroll
                    for (int r = 0; r < 16; ++r) acc += __expf(x[r][k] - m);
                    cm[e] = m; cl[e] = acc;
                }
            } else {
                float4 mm = make_float4(-3.0e38f, -3.0e38f, -3.0e38f, -3.0e38f);
#pragma unroll
                for (int r = 0; r < 16; ++r) {
                    float4 h = q3[(w*16 + r)*64 + l];
                    mm.x = fmaxf(mm.x, h.x); mm.y = fmaxf(mm.y, h.y);
                    mm.z = fmaxf(mm.z, h.z); mm.w = fmaxf(mm.w, h.w);
                }
                float4 aa = make_float4(0.f, 0.f, 0.f, 0.f);
#pragma unroll
                for (int r = 0; r < 16; ++r) {
                    float4 h = q3[(w*16 + r)*64 + l];
                    aa.x += __expf(h.x - mm.x); aa.y += __expf(h.y - mm.y);
                    aa.z += __expf(h.z - mm.z); aa.w += __expf(h.w - mm.w);
                }
                cm[0] = mm.x; cm[1] = mm.y; cm[2] = mm.z; cm[3] = mm.w;
                cl[0] = aa.x; cl[1] = aa.y; cl[2] = aa.z; cl[3] = aa.w;
            }
            // conflict-free scalar writes: lanes stride-1
#pragma unroll
            for (int e = 0; e < 4; ++e) {
                Bm[(w*4 + e)*64 + l] = cm[e];
                Bl[(w*4 + e)*64 + l] = cl[e];
            }
            __syncthreads();
            if (threadIdx.x < 256) {
                const int e  = threadIdx.x >> 6;
                const int ll = threadIdx.x & 63;
                float M = Bm[e*64 + ll], L = Bl[e*64 + ll];
#pragma unroll
                for (int w2 = 1; w2 < 8; ++w2) {
                    float m2 = Bm[(w2*4 + e)*64 + ll];
                    float l2 = Bl[(w2*4 + e)*64 + ll];
                    float mn = fmaxf(M, m2);
                    L = L * __expf(M - mn) + l2 * __expf(m2 - mn);
                    M = mn;
                }
                // storage idx (q*4+e)*64+ll  <->  actual col 256q+4*ll+e
                pm[(size_t)cu * N + (q*4 + e)*64 + ll] = M;
                pl[(size_t)cu * N + (q*4 + e)*64 + ll] = L;
            }
            __syncthreads();
        }

        grid.sync();

        // ---------- every block merges its batch's 8 partials locally ------
#pragma unroll
        for (int cc = 0; cc < 2; ++cc) {
            const int idx = threadIdx.x + cc * 512;
            float M = -3.0e38f, L = 0.f;
#pragma unroll
            for (int k2 = 0; k2 < 8; ++k2) {
                float m2 = pm[(size_t)(b*8 + k2) * N + idx];
                float l2 = pl[(size_t)(b*8 + k2) * N + idx];
                float mn = fmaxf(M, m2);
                L = L * __expf(M - mn) + l2 * __expf(m2 - mn);
                M = mn;
            }
            Lcs[idx] = M + __logf(L);
        }
        __syncthreads();
#pragma unroll
        for (int q = 0; q < 4; ++q)
#pragma unroll
            for (int e = 0; e < 4; ++e)
                Lc[q*4 + e] = Lcs[(q*4 + e)*64 + l];
        // next write to Lcs is after the next grid.sync -> no extra barrier
    }

    // ---------- final: out = exp(x - Lc) ----------
#pragma unroll
    for (int r = 0; r < 16; ++r) {
        float4* orow = (float4*)(out + rowbase + (size_t)r * N);
        float4 h = q3[(w*16 + r)*64 + l];
        float4 o;
        o.x = __expf(x[r][0] - Lc[0]);   o.y = __expf(x[r][1] - Lc[1]);
        o.z = __expf(x[r][2] - Lc[2]);   o.w = __expf(x[r][3] - Lc[3]);
        orow[l] = o;
        o.x = __expf(x[r][4] - Lc[4]);   o.y = __expf(x[r][5] - Lc[5]);
        o.z = __expf(x[r][6] - Lc[6]);   o.w = __expf(x[r][7] - Lc[7]);
        orow[64 + l] = o;
        o.x = __expf(x[r][8] - Lc[8]);   o.y = __expf(x[r][9] - Lc[9]);
        o.z = __expf(x[r][10] - Lc[10]); o.w = __expf(x[r][11] - Lc[11]);
        orow[128 + l] = o;
        o.x = __expf(h.x - Lc[12]); o.y = __expf(h.y - Lc[13]);
        o.z = __expf(h.z - Lc[14]); o.w = __expf(h.w - Lc[15]);
        orow[192 + l] = o;
    }
}

// ================= fallback: round-1 3-kernel path =================
__global__ __launch_bounds__(512, 4) void fused_pair_kernel(
    const float* __restrict__ s, const float* __restrict__ c,
    float* __restrict__ r, float* __restrict__ pm, float* __restrict__ pl,
    int has_c)
{
    const int bc    = blockIdx.x;
    const int b     = bc >> 5;
    const int chunk = bc & 31;
    const int row0  = chunk * ROWS_PER_BLK;
    const int wave  = threadIdx.x >> 6;
    const int lane  = threadIdx.x & 63;

    __shared__ float4 sm4[8][256];
    __shared__ float4 sl4[8][256];

    float4 cv[4];
    if (has_c) {
        const float4* c4 = (const float4*)(c + b * N);
#pragma unroll
        for (int k = 0; k < 4; k++) cv[k] = c4[lane + 64 * k];
    } else {
#pragma unroll
        for (int k = 0; k < 4; k++) cv[k] = make_float4(0.f, 0.f, 0.f, 0.f);
    }

    float x[4][16];
#pragma unroll
    for (int rp = 0; rp < 4; rp++) {
        const float4* srow =
            (const float4*)(s + ((size_t)(b * N + row0 + wave * 4 + rp)) * N);
#pragma unroll
        for (int k = 0; k < 4; k++) {
            float4 v = srow[lane + 64 * k];
            x[rp][4*k+0] = v.x + cv[k].x;
            x[rp][4*k+1] = v.y + cv[k].y;
            x[rp][4*k+2] = v.z + cv[k].z;
            x[rp][4*k+3] = v.w + cv[k].w;
        }
    }

    float rv[4];
#pragma unroll
    for (int rp = 0; rp < 4; rp++) {
        float m = x[rp][0];
#pragma unroll
        for (int t = 1; t < 16; t++) m = fmaxf(m, x[rp][t]);
#pragma unroll
        for (int off = 32; off > 0; off >>= 1) m = fmaxf(m, __shfl_xor(m, off, 64));
        float sum = 0.f;
#pragma unroll
        for (int t = 0; t < 16; t++) sum += __expf(x[rp][t] - m);
#pragma unroll
        for (int off = 32; off > 0; off >>= 1) sum += __shfl_xor(sum, off, 64);
        rv[rp] = -(m + __logf(sum));
        if (lane == 0) r[b * N + row0 + wave * 4 + rp] = rv[rp];
    }

#pragma unroll
    for (int k = 0; k < 4; k++) {
        float pmv[4], plv[4];
#pragma unroll
        for (int e = 0; e < 4; e++) {
            float x0 = x[0][4*k+e] + rv[0];
            float x1 = x[1][4*k+e] + rv[1];
            float x2 = x[2][4*k+e] + rv[2];
            float x3 = x[3][4*k+e] + rv[3];
            float m = fmaxf(fmaxf(x0, x1), fmaxf(x2, x3));
            plv[e] = __expf(x0 - m) + __expf(x1 - m) +
                     __expf(x2 - m) + __expf(x3 - m);
            pmv[e] = m;
        }
        sm4[wave][lane + 64 * k] = make_float4(pmv[0], pmv[1], pmv[2], pmv[3]);
        sl4[wave][lane + 64 * k] = make_float4(plv[0], plv[1], plv[2], plv[3]);
    }
    __syncthreads();

    const float* smf = (const float*)sm4;
    const float* slf = (const float*)sl4;
#pragma unroll
    for (int cc = 0; cc < 2; cc++) {
        const int col = threadIdx.x + cc * 512;
        float M = smf[col], L = slf[col];
#pragma unroll
        for (int w2 = 1; w2 < 8; w2++) {
            float m = smf[w2 * N + col], l2 = slf[w2 * N + col];
            float mn = fmaxf(M, m);
            L = L * __expf(M - mn) + l2 * __expf(m - mn);
            M = mn;
        }
        pm[(size_t)bc * N + col] = M;
        pl[(size_t)bc * N + col] = L;
    }
}

__global__ __launch_bounds__(1024) void col_combine_kernel(
    const float* __restrict__ pm, const float* __restrict__ pl,
    float* __restrict__ c)
{
    const int b  = blockIdx.x >> 2;
    const int q  = blockIdx.x & 3;
    const int jc = threadIdx.x & 255;
    const int kg = threadIdx.x >> 8;
    const int j  = q * 256 + jc;
    float M = -3.0e38f, L = 0.f;
#pragma unroll
    for (int k = 0; k < 8; k++) {
        const int kk = kg * 8 + k;
        float m = pm[((size_t)(b * PCHUNKS + kk)) * N + j];
        float l = pl[((size_t)(b * PCHUNKS + kk)) * N + j];
        float mn = fmaxf(M, m);
        L = L * __expf(M - mn) + l * __expf(m - mn); M = mn;
    }
    __shared__ float smm[4][256], sll[4][256];
    smm[kg][jc] = M; sll[kg][jc] = L;
    __syncthreads();
    if (kg == 0) {
#pragma unroll
        for (int g2 = 1; g2 < 4; g2++) {
            float m = smm[g2][jc], l = sll[g2][jc];
            float mn = fmaxf(M, m);
            L = L * __expf(M - mn) + l * __expf(m - mn); M = mn;
        }
        c[b * N + j] = -(M + __logf(L));
    }
}

__global__ __launch_bounds__(256) void zero_c_kernel(float* __restrict__ c) {
    c[blockIdx.x * 256 + threadIdx.x] = 0.0f;
}

__global__ __launch_bounds__(256) void row_lse_kernel(const float* __restrict__ s,
                                                      const float* __restrict__ c,
                                                      float* __restrict__ r) {
    const int wave = threadIdx.x >> 6;
    const int lane = threadIdx.x & 63;
    const int row  = blockIdx.x * 4 + wave;
    const int b    = row >> 10;
    const float4* srow = (const float4*)(s + (size_t)row * N);
    const float4* crow = (const float4*)(c + (size_t)b * N);
    float x[16];
#pragma unroll
    for (int k = 0; k < 4; k++) {
        float4 v = srow[lane + k * 64];
        float4 cv = crow[lane + k * 64];
        x[4*k+0]=v.x+cv.x; x[4*k+1]=v.y+cv.y; x[4*k+2]=v.z+cv.z; x[4*k+3]=v.w+cv.w;
    }
    float m = x[0];
#pragma unroll
    for (int t = 1; t < 16; t++) m = fmaxf(m, x[t]);
#pragma unroll
    for (int off = 32; off > 0; off >>= 1) m = fmaxf(m, __shfl_xor(m, off, 64));
    float sum = 0.f;
#pragma unroll
    for (int t = 0; t < 16; t++) sum += __expf(x[t] - m);
#pragma unroll
    for (int off = 32; off > 0; off >>= 1) sum += __shfl_xor(sum, off, 64);
    if (lane == 0) r[row] = -(m + __logf(sum));
}

__global__ __launch_bounds__(1024) void col_lse_direct_kernel(const float* __restrict__ s,
                                                              const float* __restrict__ r,
                                                              float* __restrict__ c) {
    const int b = blockIdx.x;
    const int j = threadIdx.x;
    const float* rb = r + b * N;
    const float* base = s + (size_t)b * N * N + j;
    float m = -3.0e38f, l = 0.f;
    for (int i = 0; i < N; i++) {
        float x  = base[(size_t)i * N] + rb[i];
        float mn = fmaxf(m, x);
        l = l * __expf(m - mn) + __expf(x - mn);
        m = mn;
    }
    c[b * N + j] = -(m + __logf(l));
}

__global__ __launch_bounds__(256) void finalize_kernel(const float* __restrict__ s,
                                                       const float* __restrict__ r,
                                                       const float* __restrict__ c,
                                                       float* __restrict__ out) {
    const int f4  = blockIdx.x * 256 + threadIdx.x;
    const int j4  = f4 & 255;
    const int row = f4 >> 8;
    const int b   = row >> 10;
    float4 v  = ((const float4*)s)[f4];
    float  rr = r[row];
    float4 cc = ((const float4*)c)[(b << 8) + j4];
    float4 o;
    o.x = __expf(v.x + rr + cc.x);
    o.y = __expf(v.y + rr + cc.y);
    o.z = __expf(v.z + rr + cc.z);
    o.w = __expf(v.w + rr + cc.w);
    ((float4*)out)[f4] = o;
}

extern "C" void kernel_launch(void* const* d_in, const int* in_sizes, int n_in,
                              void* d_out, int out_size, void* d_ws, size_t ws_size,
                              hipStream_t stream) {
    const float* s = (const float*)d_in[0];
    float* out = (float*)d_out;

    // ---- cooperative path ----
    static int coop_checked = 0, coop_ok = 0;
    if (!coop_checked) {
        int dev = 0;
        hipDeviceProp_t prop;
        if (hipGetDevice(&dev) == hipSuccess &&
            hipGetDeviceProperties(&prop, dev) == hipSuccess &&
            prop.cooperativeLaunch) {
            if (hipFuncSetAttribute((const void*)sinkhorn_coop,
                                    hipFuncAttributeMaxDynamicSharedMemorySize,
                                    LDS_BYTES) == hipSuccess)
                coop_ok = 1;
        }
        coop_checked = 1;
    }

    const size_t needed_coop = (size_t)(2 * 256 * N) * sizeof(float);
    if (coop_ok && ws_size >= needed_coop) {
        float* pmc = (float*)d_ws;             // 256*N
        float* plc = pmc + 256 * N;            // 256*N
        const float* s_arg = s;
        float* out_arg = out;
        void* kargs[] = { (void*)&s_arg, (void*)&out_arg,
                          (void*)&pmc, (void*)&plc };
        hipError_t e = hipLaunchCooperativeKernel(
            (const void*)sinkhorn_coop, dim3(256), dim3(512),
            kargs, LDS_BYTES, stream);
        if (e == hipSuccess) return;
        coop_ok = 0;  // fall through to non-coop path
    }

    // ---- fallback paths ----
    float* c  = (float*)d_ws;
    float* r  = c + BATCH * N;
    float* pm = r + BATCH * N;
    float* pl = pm + BATCH * PCHUNKS * N;

    const size_t needed =
        (size_t)(2 * BATCH * N + 2 * BATCH * PCHUNKS * N) * sizeof(float);

    if (ws_size >= needed) {
        for (int p = 0; p < 5; p++) {
            fused_pair_kernel<<<BATCH * RCHUNKS, 512, 0, stream>>>(
                s, c, r, pm, pl, p > 0 ? 1 : 0);
            col_combine_kernel<<<BATCH * 4, 1024, 0, stream>>>(pm, pl, c);
        }
    } else {
        zero_c_kernel<<<(BATCH * N) / 256, 256, 0, stream>>>(c);
        for (int it = 0; it < 10; it++) {
            if ((it & 1) == 0)
                row_lse_kernel<<<(BATCH * N) / 4, 256, 0, stream>>>(s, c, r);
            else
                col_lse_direct_kernel<<<BATCH, 1024, 0, stream>>>(s, r, c);
        }
    }

    const int total_f4 = BATCH * N * N / 4;
    finalize_kernel<<<total_f4 / 256, 256, 0, stream>>>(s, r, c, out);
}